// Round 1
// 93.905 us; speedup vs baseline: 1.0770x; 1.0770x over previous
//
#include <hip/hip_runtime.h>
#include <cstdint>

// PillarVFE fused (f32 in / f32 out), MI355X gfx950 — single-kernel version.
//
// bn(conv(feats))[o] is affine in the raw point (v0,v1,v2,v3):
//   acc_n = v0*A0 + v1*A1 + v2*A2 + v3*A3 + C0 - cx*SW07 - cy*SW18 - meanterm
//   A0=(w0+w4+w7)s  A1=(w1+w5+w8)s  A2=(w2+w6)s  A3=w3*s
//   C0=beta-mean*s  SW07=(w0+w7)s  SW18=(w1+w8)s  meanterm=(sx*SW4+sy*SW5+sz*SW6)/n
// meanterm is constant over n, so it is subtracted AFTER the max (exact).
// Masked rows (n>=npts) evaluate to C0 exactly (feats==0) — seeded via fmax(C0).
//
// v2 changes vs the 100.5 µs version:
//  - setup kernel fused away: each wave computes the 10 per-channel constants
//    in-register (W reads are L1-hot after the first block per CU); no d_ws use,
//    no serialized second launch.
//  - 16 pillars/block (4 per wave), one coalesced 8 KB stage by all 256 threads,
//    wave-uniform npts/coords hoisted ahead of __syncthreads.
//  - mirrored butterfly (shp[lane&31], 2-way LDS broadcast is free) -> 5 levels
//    instead of 6, bit-identical summation tree.
//  - point loop unrolled x2 with two independent fmax accumulators.

#define PPB 16   // pillars per block
#define PPW 4    // pillars per wave

__global__ __launch_bounds__(256) void pillar_vfe_fused(
    const float4* __restrict__ voxels4,   // [P*32] float4
    const float*  __restrict__ Wp,        // [64][9]
    const float*  __restrict__ gamma_p,   // [64]
    const float*  __restrict__ beta_p,    // [64]
    const float*  __restrict__ rmean_p,   // [64]
    const float*  __restrict__ rvar_p,    // [64]
    const int*    __restrict__ npts_p,    // [P]
    const int*    __restrict__ coords_p,  // [P][4]
    float*        __restrict__ out,       // [P][64]
    int P)
{
    __shared__ float4 sh[PPB * 32];       // 16 pillars x 32 points = 8 KB

    const int tid    = threadIdx.x;
    const int pblock = blockIdx.x * PPB;

    // ---- stage PPB pillars (8 KB), coalesced, 2 float4 per thread ----
    {
        const int base = pblock * 32;
        #pragma unroll
        for (int r = 0; r < (PPB * 32) / 256; ++r) {
            const int i = tid + r * 256;
            const int g = base + i;
            if (g < P * 32) sh[i] = voxels4[g];
        }
    }

    // ---- per-lane channel constants, in-register (overlaps staging latency) ----
    const int lane = tid & 63;
    float w[9];
    #pragma unroll
    for (int c = 0; c < 9; ++c) w[c] = Wp[lane * 9 + c];
    const float s    = gamma_p[lane] / sqrtf(rvar_p[lane] + 1e-3f);
    const float A0   = (w[0] + w[4] + w[7]) * s;
    const float A1   = (w[1] + w[5] + w[8]) * s;
    const float A2   = (w[2] + w[6]) * s;
    const float A3   = w[3] * s;
    const float C0   = beta_p[lane] - rmean_p[lane] * s;
    const float SW07 = (w[0] + w[7]) * s;
    const float SW18 = (w[1] + w[8]) * s;
    const float SW4  = w[4] * s;
    const float SW5  = w[5] * s;
    const float SW6  = w[6] * s;

    const int wave  = tid >> 6;
    const int pbase = pblock + wave * PPW;

    // wave-uniform metadata for this wave's 4 pillars (scalar loads, hoisted)
    int   npts[PPW];
    float cx[PPW], cy[PPW];
    #pragma unroll
    for (int g2 = 0; g2 < PPW; ++g2) {
        const int p = min(pbase + g2, P - 1);
        npts[g2] = npts_p[p];
        cx[g2]   = (float)coords_p[p * 4 + 3] * 0.16f + 0.08f;
        cy[g2]   = (float)coords_p[p * 4 + 2] * 0.16f + (0.08f - 39.68f);
    }

    __syncthreads();

    #pragma unroll
    for (int g2 = 0; g2 < PPW; ++g2) {
        const int p = pbase + g2;
        if (p >= P) break;
        const float4* shp = sh + (wave * PPW + g2) * 32;

        // xyz sums over ALL 32 points (reference semantics).
        // Mirrored read: both 32-lane halves load points 0..31 (2-way LDS
        // broadcast = free), then a 5-level butterfly — same summation tree
        // as the 6-level version, so bit-identical results.
        const float4 vm = shp[lane & 31];
        float sx = vm.x, sy = vm.y, sz = vm.z;
        #pragma unroll
        for (int m = 16; m >= 1; m >>= 1) {
            sx += __shfl_xor(sx, m, 64);
            sy += __shfl_xor(sy, m, 64);
            sz += __shfl_xor(sz, m, 64);
        }

        const int   n_pts = npts[g2];
        const float C1    = C0 - cx[g2] * SW07 - cy[g2] * SW18;

        // point loop (independent of the mean; deferred subtraction),
        // unrolled x2 with independent max accumulators
        float vmax0 = -3.4e38f, vmax1 = -3.4e38f;
        int n = 0;
        for (; n + 2 <= n_pts; n += 2) {
            const float4 va = shp[n];
            const float4 vb = shp[n + 1];
            float a = C1, b = C1;
            a = fmaf(va.x, A0, a);  b = fmaf(vb.x, A0, b);
            a = fmaf(va.y, A1, a);  b = fmaf(vb.y, A1, b);
            a = fmaf(va.z, A2, a);  b = fmaf(vb.z, A2, b);
            a = fmaf(va.w, A3, a);  b = fmaf(vb.w, A3, b);
            vmax0 = fmaxf(vmax0, a);
            vmax1 = fmaxf(vmax1, b);
        }
        if (n < n_pts) {
            const float4 va = shp[n];
            float a = C1;
            a = fmaf(va.x, A0, a);
            a = fmaf(va.y, A1, a);
            a = fmaf(va.z, A2, a);
            a = fmaf(va.w, A3, a);
            vmax0 = fmaxf(vmax0, a);
        }
        float vmax = fmaxf(vmax0, vmax1);

        const float inv_n    = 1.0f / (float)n_pts;
        const float meanterm = (sx * SW4 + sy * SW5 + sz * SW6) * inv_n;
        vmax -= meanterm;
        if (n_pts < 32) vmax = fmaxf(vmax, C0);   // masked rows contribute C0
        out[p * 64 + lane] = fmaxf(vmax, 0.0f);   // relu(max) == max(relu)
    }
}

extern "C" void kernel_launch(void* const* d_in, const int* in_sizes, int n_in,
                              void* d_out, int out_size, void* d_ws, size_t ws_size,
                              hipStream_t stream) {
    const float4* voxels = (const float4*)d_in[0];
    const float*  W      = (const float*)d_in[1];
    const float*  gamma_ = (const float*)d_in[2];
    const float*  beta_  = (const float*)d_in[3];
    const float*  rmean  = (const float*)d_in[4];
    const float*  rvar   = (const float*)d_in[5];
    const int*    npts   = (const int*)d_in[6];
    const int*    coords = (const int*)d_in[7];
    float*        out    = (float*)d_out;

    const int P = in_sizes[6];               // 40000

    const int blocks = (P + PPB - 1) / PPB;  // 2500 blocks x 256 threads
    pillar_vfe_fused<<<blocks, 256, 0, stream>>>(
        voxels, W, gamma_, beta_, rmean, rvar, npts, coords, out, P);
}